// Round 9
// baseline (1054.354 us; speedup 1.0000x reference)
//
#include <hip/hip_runtime.h>
#include <hip/hip_bf16.h>
#include <hip/hip_fp16.h>

// GAT fused pipeline for MI355X.
// R9: two fixes to k_msg, driven by R8 counters (VGPR=20 proved the compiler
// re-fused my load batch into per-edge load->wait->use; FETCH 253MB vs 51MB
// working set proved poor L3 retention of the fp32-stride overlay):
//  1. h16 moved to a DEDICATED tightly-packed ws buffer (256B stride, 25.6MB)
//     -> working set halves, L3 retains it (ws total 36.9MB = R4-proven).
//  2. k_msg 8-edge batch loads RAW ints (no cvt in batch) and pins the
//     load/use boundary with __builtin_amdgcn_sched_barrier(0) -> all 16
//     loads issue before the first waitcnt (true MLP=8 rows/wave).

#define N_NODES 100000
#define N_EDGE  1600000
#define N_ET    1700000   // edges + self-loops
#define N_G     100
#define HEADS   8
#define OUTC    16
#define EPS     1e-5f
#define NEG     0.2f
#define NCHUNK  3125      // 3125 * 32 == 100000

typedef unsigned int uint;
typedef unsigned short ushort;

__device__ __forceinline__ float bf2f_lo(uint u){ union{uint i; float f;} c; c.i = u << 16; return c.f; }
__device__ __forceinline__ float bf2f_hi(uint u){ union{uint i; float f;} c; c.i = u & 0xffff0000u; return c.f; }
__device__ __forceinline__ float bf2f(ushort u){ union{uint i; float f;} c; c.i = ((uint)u) << 16; return c.f; }
__device__ __forceinline__ float scrub(float v){ return (v == v) ? v : 0.f; }

__device__ __forceinline__ float ldf(const void* p, int i, int f32){
  return f32 ? ((const float*)p)[i] : bf2f(((const ushort*)p)[i]);
}
__device__ __forceinline__ int ldid(const int* p, int flat, int is64){
  return is64 ? p[2 * flat] : p[flat];
}

// ---------------- dtype detection ----------------
__global__ void k_detect(const uint* __restrict__ x32, const int* __restrict__ ei32,
                         const int* __restrict__ b32, int* __restrict__ flags){
  __shared__ int cnt[3];
  int t = threadIdx.x;
  if (t < 3) cnt[t] = 0;
  __syncthreads();
  { uint w = x32[t]; uint el = (w >> 7) & 0xffu;
    if (el != 0 && (el < 110 || el > 140)) atomicAdd(&cnt[0], 1); }
  if (t < 128){ if (ei32[2 * t + 1] != 0) atomicAdd(&cnt[1], 1); }
  if (t < 128){ if (b32[98001 + 2 * t] != 0) atomicAdd(&cnt[2], 1); }
  __syncthreads();
  if (t == 0){
    flags[0] = cnt[0] > 64;  // 1 = floats are fp32
    flags[1] = cnt[1] < 32;  // 1 = edge_index is int64
    flags[2] = cnt[2] < 32;  // 1 = batch is int64
    flags[3] = 0;
  }
}

// ---------------- BN statistics: column sum / sumsq ----------------
__global__ __launch_bounds__(256) void k_bn_stats(const void* __restrict__ xraw,
                                                  const int* __restrict__ flags,
                                                  float* __restrict__ stats){
  int f32 = flags[0];
  int t = threadIdx.x;
  int c = t & 63;
  int c0 = c * 2;
  float s0 = 0.f, s1 = 0.f, q0 = 0.f, q1 = 0.f;
  if (f32){
    const float2* x2 = (const float2*)xraw;
    for (int r = blockIdx.x * 4 + (t >> 6); r < N_NODES; r += gridDim.x * 4){
      float2 v = x2[r * 64 + c];
      float f0 = scrub(v.x), f1 = scrub(v.y);
      s0 += f0; q0 += f0 * f0;
      s1 += f1; q1 += f1 * f1;
    }
  } else {
    const uint* x2 = (const uint*)xraw;
    for (int r = blockIdx.x * 4 + (t >> 6); r < N_NODES; r += gridDim.x * 4){
      uint v = x2[r * 64 + c];
      float f0 = scrub(bf2f_lo(v)), f1 = scrub(bf2f_hi(v));
      s0 += f0; q0 += f0 * f0;
      s1 += f1; q1 += f1 * f1;
    }
  }
  __shared__ float red[4][256];
  red[0][t] = s0; red[1][t] = q0; red[2][t] = s1; red[3][t] = q1;
  __syncthreads();
  if (t < 64){
    s0 = red[0][t] + red[0][t+64] + red[0][t+128] + red[0][t+192];
    q0 = red[1][t] + red[1][t+64] + red[1][t+128] + red[1][t+192];
    s1 = red[2][t] + red[2][t+64] + red[2][t+128] + red[2][t+192];
    q1 = red[3][t] + red[3][t+64] + red[3][t+128] + red[3][t+192];
    atomicAdd(&stats[c0],       s0);
    atomicAdd(&stats[c0+1],     s1);
    atomicAdd(&stats[128+c0],   q0);
    atomicAdd(&stats[128+c0+1], q1);
  }
}

// ------------- fold BN into GEMM: Wp = scale*W, bp = shift @ W ---------------
__global__ __launch_bounds__(128) void k_prep(const float* __restrict__ stats,
                                              const void* __restrict__ gamma,
                                              const void* __restrict__ beta,
                                              const void* __restrict__ W,
                                              const int* __restrict__ flags,
                                              float* __restrict__ Wp, float* __restrict__ bp){
  int f32 = flags[0];
  __shared__ float scl[128], shf[128];
  int t = threadIdx.x;
  float mean = scrub(stats[t] * (1.0f / N_NODES));
  float var  = stats[128 + t] * (1.0f / N_NODES) - mean * mean;
  if (!(var > 0.f)) var = 0.f;
  float sc = scrub(ldf(gamma, t, f32)) * rsqrtf(var + EPS);
  sc = scrub(sc);
  scl[t] = sc;
  shf[t] = scrub(scrub(ldf(beta, t, f32)) - mean * sc);
  __syncthreads();
  float b = 0.f;
  for (int c = 0; c < 128; c++){
    float w = scrub(ldf(W, c * 128 + t, f32));
    Wp[c * 128 + t] = scl[c] * w;
    b += shf[c] * w;
  }
  bp[t] = scrub(b);
}

// -------- GEMM h = x @ Wp + bp  -> dedicated h16 [N][128] (256B stride) ------
__global__ __launch_bounds__(256) void k_gemm(const void* __restrict__ xraw,
                                              const float* __restrict__ Wp,
                                              const float* __restrict__ bp,
                                              const int* __restrict__ flags,
                                              __half* __restrict__ h16){
  int f32 = flags[0];
  __shared__ float As[8][132];
  __shared__ float Bs[8][132];
  int t = threadIdx.x;
  int tx = t & 15, ty = t >> 4;
  int row0 = blockIdx.x * 128;
  float acc[8][8];
#pragma unroll
  for (int i = 0; i < 8; i++)
#pragma unroll
    for (int u = 0; u < 8; u++) acc[i][u] = 0.f;

  int ar = t >> 1, ak = (t & 1) * 4;
  int bk = t >> 5, bj = (t & 31) * 4;
  for (int k0 = 0; k0 < 128; k0 += 8){
    int grow = row0 + ar;
    float a0v = 0.f, a1v = 0.f, a2v = 0.f, a3v = 0.f;
    if (grow < N_NODES){
      if (f32){
        float4 r4 = *(const float4*)((const float*)xraw + (size_t)grow * 128 + k0 + ak);
        a0v = scrub(r4.x); a1v = scrub(r4.y); a2v = scrub(r4.z); a3v = scrub(r4.w);
      } else {
        uint2 raw = *(const uint2*)((const ushort*)xraw + (size_t)grow * 128 + k0 + ak);
        a0v = scrub(bf2f_lo(raw.x)); a1v = scrub(bf2f_hi(raw.x));
        a2v = scrub(bf2f_lo(raw.y)); a3v = scrub(bf2f_hi(raw.y));
      }
    }
    As[ak+0][ar] = a0v; As[ak+1][ar] = a1v; As[ak+2][ar] = a2v; As[ak+3][ar] = a3v;
    float4 wb = *(const float4*)(Wp + (k0 + bk) * 128 + bj);
    *(float4*)&Bs[bk][bj] = wb;
    __syncthreads();
#pragma unroll
    for (int k = 0; k < 8; k++){
      float4 a0 = *(const float4*)&As[k][ty * 8];
      float4 a1 = *(const float4*)&As[k][ty * 8 + 4];
      float4 b0 = *(const float4*)&Bs[k][tx * 4];
      float4 b1 = *(const float4*)&Bs[k][64 + tx * 4];
      float a[8] = {a0.x,a0.y,a0.z,a0.w,a1.x,a1.y,a1.z,a1.w};
      float b[8] = {b0.x,b0.y,b0.z,b0.w,b1.x,b1.y,b1.z,b1.w};
#pragma unroll
      for (int i = 0; i < 8; i++)
#pragma unroll
        for (int u = 0; u < 8; u++) acc[i][u] += a[i] * b[u];
    }
    __syncthreads();
  }
  float4 bl = *(const float4*)(bp + tx * 4);
  float4 bh = *(const float4*)(bp + 64 + tx * 4);
  float bb[8] = {bl.x,bl.y,bl.z,bl.w,bh.x,bh.y,bh.z,bh.w};
#pragma unroll
  for (int i = 0; i < 8; i++){
    int r = row0 + ty * 8 + i;
    if (r >= N_NODES) break;
    __half* po = h16 + (size_t)r * 128;
    float o[8];
#pragma unroll
    for (int u = 0; u < 8; u++) o[u] = scrub(acc[i][u] + bb[u]);
    *(__half2*)(po + tx * 4)          = __floats2half2_rn(o[0], o[1]);
    *(__half2*)(po + tx * 4 + 2)      = __floats2half2_rn(o[2], o[3]);
    *(__half2*)(po + 64 + tx * 4)     = __floats2half2_rn(o[4], o[5]);
    *(__half2*)(po + 64 + tx * 4 + 2) = __floats2half2_rn(o[6], o[7]);
  }
}

// ------------- attention scalars a_src, a_dst per (node, head), fp16 ---------
__global__ __launch_bounds__(256) void k_attn(const __half* __restrict__ h16,
                                              const void* __restrict__ att_src,
                                              const void* __restrict__ att_dst,
                                              const int* __restrict__ flags,
                                              __half* __restrict__ a_src16, __half* __restrict__ a_dst16){
  int f32 = flags[0];
  __shared__ float ss[128], sd[128];
  int t = threadIdx.x;
  if (t < 128){ ss[t] = scrub(ldf(att_src, t, f32)); sd[t] = scrub(ldf(att_dst, t, f32)); }
  __syncthreads();
  int idx = blockIdx.x * 256 + t;     // exactly N_NODES*8 threads
  int n = idx >> 3, h = idx & 7;
  const uint4* row = (const uint4*)(h16 + (size_t)n * 128 + h * 16);
  uint4 r0 = row[0], r1 = row[1];
  uint u[8] = {r0.x,r0.y,r0.z,r0.w,r1.x,r1.y,r1.z,r1.w};
  float as = 0.f, ad = 0.f;
#pragma unroll
  for (int j = 0; j < 8; j++){
    __half2 hh = *(__half2*)&u[j];
    float2 f = __half22float2(hh);
    as += f.x * ss[h*16 + 2*j] + f.y * ss[h*16 + 2*j + 1];
    ad += f.x * sd[h*16 + 2*j] + f.y * sd[h*16 + 2*j + 1];
  }
  a_src16[idx] = __float2half_rn(scrub(as));
  a_dst16[idx] = __float2half_rn(scrub(ad));
}

// ------------------------------ CSR build ------------------------------------
__global__ void k_deg(const int* __restrict__ ei, const int* __restrict__ flags,
                      int* __restrict__ deg){
  int is64 = flags[1];
  for (int e = blockIdx.x * blockDim.x + threadIdx.x; e < N_ET; e += gridDim.x * blockDim.x){
    int d = (e < N_EDGE) ? ldid(ei, N_EDGE + e, is64) : (e - N_EDGE);
    if ((uint)d < N_NODES) atomicAdd(&deg[d], 1);
  }
}

__global__ void k_scan1(const int* __restrict__ deg, int* __restrict__ chunk){
  int i = blockIdx.x * blockDim.x + threadIdx.x;
  if (i >= NCHUNK) return;
  const int4* dp = (const int4*)(deg + i * 32);
  int s = 0;
#pragma unroll
  for (int j = 0; j < 8; j++){ int4 v = dp[j]; s += v.x + v.y + v.z + v.w; }
  chunk[i] = s;
}

__global__ __launch_bounds__(1024) void k_scan2(int* __restrict__ chunk){
  __shared__ int sdat[1024];
  int t = threadIdx.x;
  int v[4]; int tot = 0;
#pragma unroll
  for (int j = 0; j < 4; j++){
    int c = t * 4 + j;
    v[j] = (c < NCHUNK) ? chunk[c] : 0;
    tot += v[j];
  }
  sdat[t] = tot;
  __syncthreads();
  for (int off = 1; off < 1024; off <<= 1){
    int add = (t >= off) ? sdat[t - off] : 0;
    __syncthreads();
    sdat[t] += add;
    __syncthreads();
  }
  int run = sdat[t] - tot;   // exclusive
#pragma unroll
  for (int j = 0; j < 4; j++){
    int c = t * 4 + j;
    if (c < NCHUNK) chunk[c] = run;
    run += v[j];
  }
}

__global__ void k_scan3(const int* __restrict__ deg, const int* __restrict__ chunk, int* __restrict__ offsets){
  int i = blockIdx.x * blockDim.x + threadIdx.x;
  if (i >= NCHUNK) return;
  int run = chunk[i];
  for (int j = 0; j < 32; j++){
    int idx = i * 32 + j;
    offsets[idx] = run;
    run += deg[idx];
  }
  if (i == NCHUNK - 1) offsets[N_NODES] = run;
}

__global__ void k_scatter(const int* __restrict__ ei, const int* __restrict__ flags,
                          const int* __restrict__ offsets, int* __restrict__ cursor, int* __restrict__ csr){
  int is64 = flags[1];
  for (int e = blockIdx.x * blockDim.x + threadIdx.x; e < N_ET; e += gridDim.x * blockDim.x){
    int s, d;
    if (e < N_EDGE){ s = ldid(ei, e, is64); d = ldid(ei, N_EDGE + e, is64); }
    else { s = e - N_EDGE; d = s; }
    if ((uint)d >= N_NODES) continue;
    int pos = atomicAdd(&cursor[d], 1);
    int slot = offsets[d] + pos;
    if ((uint)slot < N_ET) csr[slot] = s;
  }
}

// ------ fused: inline softmax + gather + head-mean + ELU + pool.
// One wave per node, lane owns halves 2*lane,2*lane+1 (head myh=lane>>3).
// 8-edge batch: 8 shfl -> 16 RAW int loads -> sched_barrier(0) -> cvt+math.
__global__ __launch_bounds__(256) void k_msg(const int* __restrict__ offsets, const int* __restrict__ csr,
                                             const __half* __restrict__ a_src16, const __half* __restrict__ a_dst16,
                                             const __half* __restrict__ h16, const void* __restrict__ bias,
                                             const int* __restrict__ batch, const int* __restrict__ flags,
                                             float* __restrict__ pool, float* __restrict__ cntg){
  int f32 = flags[0], b64 = flags[2];
  int t = threadIdx.x;
  int wv = t >> 6, lane = t & 63;
  int n = blockIdx.x * 4 + wv;        // grid = N/4 exactly
  int myh = lane >> 3;
  int start = offsets[n], end = offsets[n + 1];
  float ad = __half2float(a_dst16[(size_t)n * 8 + myh]);
  const ushort* as16 = (const ushort*)a_src16;
  float acc0 = 0.f, acc1 = 0.f, den = 0.f;

  for (int base = start; base < end; base += 64){
    int cnt = min(64, end - base);
    int sreg = csr[min(base + lane, N_ET - 1)];
    for (int jj = 0; jj < cnt; jj += 8){
      int s[8];
#pragma unroll
      for (int u = 0; u < 8; u++) s[u] = __shfl(sreg, jj + u);
      ushort araw[8]; uint hraw[8];
#pragma unroll
      for (int u = 0; u < 8; u++){
        araw[u] = as16[(size_t)s[u] * 8 + myh];
        hraw[u] = ((const uint*)(h16 + (size_t)s[u] * 128))[lane];
      }
      __builtin_amdgcn_sched_barrier(0);   // pin: all 16 loads issue first
#pragma unroll
      for (int u = 0; u < 8; u++){
        float e = __half2float(*(__half*)&araw[u]) + ad;
        e = e > 0.f ? e : NEG * e;
        float p = (jj + u < cnt) ? __expf(fminf(e, 30.f)) : 0.f;
        float2 hv = __half22float2(*(__half2*)&hraw[u]);
        den  += p;
        acc0 += p * hv.x;
        acc1 += p * hv.y;
      }
    }
  }

  float inv = (den > 0.f) ? (1.0f / den) : 0.f;   // den>0 via self-loop
  float v0 = acc0 * inv, v1 = acc1 * inv;
  // head mean: sum over lane bits 3,4,5 (heads)
  v0 += __shfl_xor(v0, 8);  v1 += __shfl_xor(v1, 8);
  v0 += __shfl_xor(v0, 16); v1 += __shfl_xor(v1, 16);
  v0 += __shfl_xor(v0, 32); v1 += __shfl_xor(v1, 32);
  if (lane < 8){
    int c0 = lane * 2;
    float o0 = v0 * 0.125f + scrub(ldf(bias, c0, f32));
    float o1 = v1 * 0.125f + scrub(ldf(bias, c0 + 1, f32));
    o0 = o0 > 0.f ? o0 : (__expf(o0) - 1.0f);
    o1 = o1 > 0.f ? o1 : (__expf(o1) - 1.0f);
    int g = ldid(batch, n, b64);
    if ((uint)g < N_G){
      atomicAdd(&pool[g * 16 + c0],     scrub(o0));
      atomicAdd(&pool[g * 16 + c0 + 1], scrub(o1));
      if (lane == 0) atomicAdd(&cntg[g], 1.0f);
    }
  }
}

// ---- final: divide by counts, write FP32 (reference output dtype) ----
__global__ void k_final(const float* __restrict__ pool, const float* __restrict__ cntg,
                        float* __restrict__ out){
  int i = blockIdx.x * blockDim.x + threadIdx.x;
  if (i >= N_G * OUTC) return;
  int g = i >> 4;
  out[i] = scrub(pool[i] / fmaxf(cntg[g], 1.0f));
}

// -----------------------------------------------------------------------------
extern "C" void kernel_launch(void* const* d_in, const int* in_sizes, int n_in,
                              void* d_out, int out_size, void* d_ws, size_t ws_size,
                              hipStream_t stream){
  (void)in_sizes; (void)n_in; (void)out_size; (void)ws_size;
  const void* x     = d_in[0];
  const int*  ei    = (const int*)d_in[1];
  const int*  batch = (const int*)d_in[2];
  const void* gamma = d_in[3];
  const void* beta  = d_in[4];
  const void* W     = d_in[5];
  const void* att_s = d_in[6];
  const void* att_d = d_in[7];
  const void* bias  = d_in[8];

  // ws total ~36.9 MB (R4-proven safe). h16 tightly packed; csr last.
  char* ws = (char*)d_ws;
  size_t off = 0;
  auto alloc = [&](size_t b){ size_t r = off; off += (b + 255) & ~(size_t)255; return r; };
  int*    flags   = (int*)(ws + alloc(4 * 4));
  float*  stats   = (float*)(ws + alloc(256 * 4));
  float*  Wp      = (float*)(ws + alloc(16384 * 4));
  float*  bp      = (float*)(ws + alloc(128 * 4));
  float*  pool    = (float*)(ws + alloc(N_G * 16 * 4));
  float*  cntg    = (float*)(ws + alloc(N_G * 4));
  int*    chunk   = (int*)(ws + alloc(4096 * 4));
  int*    offsets = (int*)(ws + alloc((size_t)(N_NODES + 1) * 4));
  int*    deg     = (int*)(ws + alloc((size_t)N_NODES * 4));
  int*    cursor  = (int*)(ws + alloc((size_t)N_NODES * 4));
  __half* a_src16 = (__half*)(ws + alloc((size_t)N_NODES * 8 * 2));
  __half* a_dst16 = (__half*)(ws + alloc((size_t)N_NODES * 8 * 2));
  __half* h16     = (__half*)(ws + alloc((size_t)N_NODES * 128 * 2));
  int*    csr     = (int*)(ws + alloc((size_t)N_ET * 4));

  hipMemsetAsync(stats,  0, 256 * 4, stream);
  hipMemsetAsync(deg,    0, (size_t)N_NODES * 4, stream);
  hipMemsetAsync(cursor, 0, (size_t)N_NODES * 4, stream);
  hipMemsetAsync(pool,   0, N_G * 16 * 4, stream);
  hipMemsetAsync(cntg,   0, N_G * 4, stream);

  k_detect<<<1, 256, 0, stream>>>((const uint*)x, ei, batch, flags);
  k_bn_stats<<<512, 256, 0, stream>>>(x, flags, stats);
  k_prep<<<1, 128, 0, stream>>>(stats, gamma, beta, W, flags, Wp, bp);
  k_gemm<<<(N_NODES + 127) / 128, 256, 0, stream>>>(x, Wp, bp, flags, h16);
  k_attn<<<(N_NODES * 8) / 256, 256, 0, stream>>>(h16, att_s, att_d, flags, a_src16, a_dst16);
  k_deg<<<1024, 256, 0, stream>>>(ei, flags, deg);
  k_scan1<<<(NCHUNK + 255) / 256, 256, 0, stream>>>(deg, chunk);
  k_scan2<<<1, 1024, 0, stream>>>(chunk);
  k_scan3<<<(NCHUNK + 255) / 256, 256, 0, stream>>>(deg, chunk, offsets);
  k_scatter<<<1024, 256, 0, stream>>>(ei, flags, offsets, cursor, csr);
  k_msg<<<N_NODES / 4, 256, 0, stream>>>(offsets, csr, a_src16, a_dst16, h16, bias, batch, flags, pool, cntg);
  k_final<<<(N_G * OUTC + 255) / 256, 256, 0, stream>>>(pool, cntg, (float*)d_out);
}

// Round 10
// 1040.029 us; speedup vs baseline: 1.0138x; 1.0138x over previous
//
#include <hip/hip_runtime.h>
#include <hip/hip_bf16.h>
#include <hip/hip_fp16.h>

// GAT fused pipeline for MI355X.
// R10: k_msg 8-edge batch with 16 INDIVIDUALLY NAMED scalar loads (no
// arrays -> compiler cannot demote to scratch; R8/R9's VGPR=20 proved the
// array-based batch was serialized to load->wait->use per edge). Raw int
// loads, sched_barrier(0) after the batch, cvt+math after. Expect VGPR ~50.
// Decisive experiment: MLP theory -> k_msg ~250us; L2-miss-path-plateau
// theory (R6/R8/R9 all pin at 410-460 GB/s) -> ~540us.

#define N_NODES 100000
#define N_EDGE  1600000
#define N_ET    1700000   // edges + self-loops
#define N_G     100
#define HEADS   8
#define OUTC    16
#define EPS     1e-5f
#define NEG     0.2f
#define NCHUNK  3125      // 3125 * 32 == 100000

typedef unsigned int uint;
typedef unsigned short ushort;

__device__ __forceinline__ float bf2f_lo(uint u){ union{uint i; float f;} c; c.i = u << 16; return c.f; }
__device__ __forceinline__ float bf2f_hi(uint u){ union{uint i; float f;} c; c.i = u & 0xffff0000u; return c.f; }
__device__ __forceinline__ float bf2f(ushort u){ union{uint i; float f;} c; c.i = ((uint)u) << 16; return c.f; }
__device__ __forceinline__ float scrub(float v){ return (v == v) ? v : 0.f; }

__device__ __forceinline__ float ldf(const void* p, int i, int f32){
  return f32 ? ((const float*)p)[i] : bf2f(((const ushort*)p)[i]);
}
__device__ __forceinline__ int ldid(const int* p, int flat, int is64){
  return is64 ? p[2 * flat] : p[flat];
}

// ---------------- dtype detection ----------------
__global__ void k_detect(const uint* __restrict__ x32, const int* __restrict__ ei32,
                         const int* __restrict__ b32, int* __restrict__ flags){
  __shared__ int cnt[3];
  int t = threadIdx.x;
  if (t < 3) cnt[t] = 0;
  __syncthreads();
  { uint w = x32[t]; uint el = (w >> 7) & 0xffu;
    if (el != 0 && (el < 110 || el > 140)) atomicAdd(&cnt[0], 1); }
  if (t < 128){ if (ei32[2 * t + 1] != 0) atomicAdd(&cnt[1], 1); }
  if (t < 128){ if (b32[98001 + 2 * t] != 0) atomicAdd(&cnt[2], 1); }
  __syncthreads();
  if (t == 0){
    flags[0] = cnt[0] > 64;  // 1 = floats are fp32
    flags[1] = cnt[1] < 32;  // 1 = edge_index is int64
    flags[2] = cnt[2] < 32;  // 1 = batch is int64
    flags[3] = 0;
  }
}

// ---------------- BN statistics: column sum / sumsq ----------------
__global__ __launch_bounds__(256) void k_bn_stats(const void* __restrict__ xraw,
                                                  const int* __restrict__ flags,
                                                  float* __restrict__ stats){
  int f32 = flags[0];
  int t = threadIdx.x;
  int c = t & 63;
  int c0 = c * 2;
  float s0 = 0.f, s1 = 0.f, q0 = 0.f, q1 = 0.f;
  if (f32){
    const float2* x2 = (const float2*)xraw;
    for (int r = blockIdx.x * 4 + (t >> 6); r < N_NODES; r += gridDim.x * 4){
      float2 v = x2[r * 64 + c];
      float f0 = scrub(v.x), f1 = scrub(v.y);
      s0 += f0; q0 += f0 * f0;
      s1 += f1; q1 += f1 * f1;
    }
  } else {
    const uint* x2 = (const uint*)xraw;
    for (int r = blockIdx.x * 4 + (t >> 6); r < N_NODES; r += gridDim.x * 4){
      uint v = x2[r * 64 + c];
      float f0 = scrub(bf2f_lo(v)), f1 = scrub(bf2f_hi(v));
      s0 += f0; q0 += f0 * f0;
      s1 += f1; q1 += f1 * f1;
    }
  }
  __shared__ float red[4][256];
  red[0][t] = s0; red[1][t] = q0; red[2][t] = s1; red[3][t] = q1;
  __syncthreads();
  if (t < 64){
    s0 = red[0][t] + red[0][t+64] + red[0][t+128] + red[0][t+192];
    q0 = red[1][t] + red[1][t+64] + red[1][t+128] + red[1][t+192];
    s1 = red[2][t] + red[2][t+64] + red[2][t+128] + red[2][t+192];
    q1 = red[3][t] + red[3][t+64] + red[3][t+128] + red[3][t+192];
    atomicAdd(&stats[c0],       s0);
    atomicAdd(&stats[c0+1],     s1);
    atomicAdd(&stats[128+c0],   q0);
    atomicAdd(&stats[128+c0+1], q1);
  }
}

// ------------- fold BN into GEMM: Wp = scale*W, bp = shift @ W ---------------
__global__ __launch_bounds__(128) void k_prep(const float* __restrict__ stats,
                                              const void* __restrict__ gamma,
                                              const void* __restrict__ beta,
                                              const void* __restrict__ W,
                                              const int* __restrict__ flags,
                                              float* __restrict__ Wp, float* __restrict__ bp){
  int f32 = flags[0];
  __shared__ float scl[128], shf[128];
  int t = threadIdx.x;
  float mean = scrub(stats[t] * (1.0f / N_NODES));
  float var  = stats[128 + t] * (1.0f / N_NODES) - mean * mean;
  if (!(var > 0.f)) var = 0.f;
  float sc = scrub(ldf(gamma, t, f32)) * rsqrtf(var + EPS);
  sc = scrub(sc);
  scl[t] = sc;
  shf[t] = scrub(scrub(ldf(beta, t, f32)) - mean * sc);
  __syncthreads();
  float b = 0.f;
  for (int c = 0; c < 128; c++){
    float w = scrub(ldf(W, c * 128 + t, f32));
    Wp[c * 128 + t] = scl[c] * w;
    b += shf[c] * w;
  }
  bp[t] = scrub(b);
}

// -------- GEMM h = x @ Wp + bp  -> dedicated h16 [N][128] (256B stride) ------
__global__ __launch_bounds__(256) void k_gemm(const void* __restrict__ xraw,
                                              const float* __restrict__ Wp,
                                              const float* __restrict__ bp,
                                              const int* __restrict__ flags,
                                              __half* __restrict__ h16){
  int f32 = flags[0];
  __shared__ float As[8][132];
  __shared__ float Bs[8][132];
  int t = threadIdx.x;
  int tx = t & 15, ty = t >> 4;
  int row0 = blockIdx.x * 128;
  float acc[8][8];
#pragma unroll
  for (int i = 0; i < 8; i++)
#pragma unroll
    for (int u = 0; u < 8; u++) acc[i][u] = 0.f;

  int ar = t >> 1, ak = (t & 1) * 4;
  int bk = t >> 5, bj = (t & 31) * 4;
  for (int k0 = 0; k0 < 128; k0 += 8){
    int grow = row0 + ar;
    float a0v = 0.f, a1v = 0.f, a2v = 0.f, a3v = 0.f;
    if (grow < N_NODES){
      if (f32){
        float4 r4 = *(const float4*)((const float*)xraw + (size_t)grow * 128 + k0 + ak);
        a0v = scrub(r4.x); a1v = scrub(r4.y); a2v = scrub(r4.z); a3v = scrub(r4.w);
      } else {
        uint2 raw = *(const uint2*)((const ushort*)xraw + (size_t)grow * 128 + k0 + ak);
        a0v = scrub(bf2f_lo(raw.x)); a1v = scrub(bf2f_hi(raw.x));
        a2v = scrub(bf2f_lo(raw.y)); a3v = scrub(bf2f_hi(raw.y));
      }
    }
    As[ak+0][ar] = a0v; As[ak+1][ar] = a1v; As[ak+2][ar] = a2v; As[ak+3][ar] = a3v;
    float4 wb = *(const float4*)(Wp + (k0 + bk) * 128 + bj);
    *(float4*)&Bs[bk][bj] = wb;
    __syncthreads();
#pragma unroll
    for (int k = 0; k < 8; k++){
      float4 a0 = *(const float4*)&As[k][ty * 8];
      float4 a1 = *(const float4*)&As[k][ty * 8 + 4];
      float4 b0 = *(const float4*)&Bs[k][tx * 4];
      float4 b1 = *(const float4*)&Bs[k][64 + tx * 4];
      float a[8] = {a0.x,a0.y,a0.z,a0.w,a1.x,a1.y,a1.z,a1.w};
      float b[8] = {b0.x,b0.y,b0.z,b0.w,b1.x,b1.y,b1.z,b1.w};
#pragma unroll
      for (int i = 0; i < 8; i++)
#pragma unroll
        for (int u = 0; u < 8; u++) acc[i][u] += a[i] * b[u];
    }
    __syncthreads();
  }
  float4 bl = *(const float4*)(bp + tx * 4);
  float4 bh = *(const float4*)(bp + 64 + tx * 4);
  float bb[8] = {bl.x,bl.y,bl.z,bl.w,bh.x,bh.y,bh.z,bh.w};
#pragma unroll
  for (int i = 0; i < 8; i++){
    int r = row0 + ty * 8 + i;
    if (r >= N_NODES) break;
    __half* po = h16 + (size_t)r * 128;
    float o[8];
#pragma unroll
    for (int u = 0; u < 8; u++) o[u] = scrub(acc[i][u] + bb[u]);
    *(__half2*)(po + tx * 4)          = __floats2half2_rn(o[0], o[1]);
    *(__half2*)(po + tx * 4 + 2)      = __floats2half2_rn(o[2], o[3]);
    *(__half2*)(po + 64 + tx * 4)     = __floats2half2_rn(o[4], o[5]);
    *(__half2*)(po + 64 + tx * 4 + 2) = __floats2half2_rn(o[6], o[7]);
  }
}

// ------------- attention scalars a_src, a_dst per (node, head), fp16 ---------
__global__ __launch_bounds__(256) void k_attn(const __half* __restrict__ h16,
                                              const void* __restrict__ att_src,
                                              const void* __restrict__ att_dst,
                                              const int* __restrict__ flags,
                                              __half* __restrict__ a_src16, __half* __restrict__ a_dst16){
  int f32 = flags[0];
  __shared__ float ss[128], sd[128];
  int t = threadIdx.x;
  if (t < 128){ ss[t] = scrub(ldf(att_src, t, f32)); sd[t] = scrub(ldf(att_dst, t, f32)); }
  __syncthreads();
  int idx = blockIdx.x * 256 + t;     // exactly N_NODES*8 threads
  int n = idx >> 3, h = idx & 7;
  const uint4* row = (const uint4*)(h16 + (size_t)n * 128 + h * 16);
  uint4 r0 = row[0], r1 = row[1];
  uint u[8] = {r0.x,r0.y,r0.z,r0.w,r1.x,r1.y,r1.z,r1.w};
  float as = 0.f, ad = 0.f;
#pragma unroll
  for (int j = 0; j < 8; j++){
    __half2 hh = *(__half2*)&u[j];
    float2 f = __half22float2(hh);
    as += f.x * ss[h*16 + 2*j] + f.y * ss[h*16 + 2*j + 1];
    ad += f.x * sd[h*16 + 2*j] + f.y * sd[h*16 + 2*j + 1];
  }
  a_src16[idx] = __float2half_rn(scrub(as));
  a_dst16[idx] = __float2half_rn(scrub(ad));
}

// ------------------------------ CSR build ------------------------------------
__global__ void k_deg(const int* __restrict__ ei, const int* __restrict__ flags,
                      int* __restrict__ deg){
  int is64 = flags[1];
  for (int e = blockIdx.x * blockDim.x + threadIdx.x; e < N_ET; e += gridDim.x * blockDim.x){
    int d = (e < N_EDGE) ? ldid(ei, N_EDGE + e, is64) : (e - N_EDGE);
    if ((uint)d < N_NODES) atomicAdd(&deg[d], 1);
  }
}

__global__ void k_scan1(const int* __restrict__ deg, int* __restrict__ chunk){
  int i = blockIdx.x * blockDim.x + threadIdx.x;
  if (i >= NCHUNK) return;
  const int4* dp = (const int4*)(deg + i * 32);
  int s = 0;
#pragma unroll
  for (int j = 0; j < 8; j++){ int4 v = dp[j]; s += v.x + v.y + v.z + v.w; }
  chunk[i] = s;
}

__global__ __launch_bounds__(1024) void k_scan2(int* __restrict__ chunk){
  __shared__ int sdat[1024];
  int t = threadIdx.x;
  int v[4]; int tot = 0;
#pragma unroll
  for (int j = 0; j < 4; j++){
    int c = t * 4 + j;
    v[j] = (c < NCHUNK) ? chunk[c] : 0;
    tot += v[j];
  }
  sdat[t] = tot;
  __syncthreads();
  for (int off = 1; off < 1024; off <<= 1){
    int add = (t >= off) ? sdat[t - off] : 0;
    __syncthreads();
    sdat[t] += add;
    __syncthreads();
  }
  int run = sdat[t] - tot;   // exclusive
#pragma unroll
  for (int j = 0; j < 4; j++){
    int c = t * 4 + j;
    if (c < NCHUNK) chunk[c] = run;
    run += v[j];
  }
}

__global__ void k_scan3(const int* __restrict__ deg, const int* __restrict__ chunk, int* __restrict__ offsets){
  int i = blockIdx.x * blockDim.x + threadIdx.x;
  if (i >= NCHUNK) return;
  int run = chunk[i];
  for (int j = 0; j < 32; j++){
    int idx = i * 32 + j;
    offsets[idx] = run;
    run += deg[idx];
  }
  if (i == NCHUNK - 1) offsets[N_NODES] = run;
}

__global__ void k_scatter(const int* __restrict__ ei, const int* __restrict__ flags,
                          const int* __restrict__ offsets, int* __restrict__ cursor, int* __restrict__ csr){
  int is64 = flags[1];
  for (int e = blockIdx.x * blockDim.x + threadIdx.x; e < N_ET; e += gridDim.x * blockDim.x){
    int s, d;
    if (e < N_EDGE){ s = ldid(ei, e, is64); d = ldid(ei, N_EDGE + e, is64); }
    else { s = e - N_EDGE; d = s; }
    if ((uint)d >= N_NODES) continue;
    int pos = atomicAdd(&cursor[d], 1);
    int slot = offsets[d] + pos;
    if ((uint)slot < N_ET) csr[slot] = s;
  }
}

// ------ fused: inline softmax + gather + head-mean + ELU + pool.
// One wave per node, lane owns halves 2*lane,2*lane+1 (head myh=lane>>3).
// 8-edge batch, 16 NAMED scalar loads -> sched_barrier(0) -> cvt+math.
__global__ __launch_bounds__(256) void k_msg(const int* __restrict__ offsets, const int* __restrict__ csr,
                                             const __half* __restrict__ a_src16, const __half* __restrict__ a_dst16,
                                             const __half* __restrict__ h16, const void* __restrict__ bias,
                                             const int* __restrict__ batch, const int* __restrict__ flags,
                                             float* __restrict__ pool, float* __restrict__ cntg){
  int f32 = flags[0], b64 = flags[2];
  int t = threadIdx.x;
  int wv = t >> 6, lane = t & 63;
  int n = blockIdx.x * 4 + wv;        // grid = N/4 exactly
  int myh = lane >> 3;
  int start = offsets[n], end = offsets[n + 1];
  float ad = __half2float(a_dst16[(size_t)n * 8 + myh]);
  const ushort* as16 = (const ushort*)a_src16;
  const uint* h32 = (const uint*)h16;   // row r at h32[r*64 + lane]
  float acc0 = 0.f, acc1 = 0.f, den = 0.f;

  for (int base = start; base < end; base += 64){
    int cnt = min(64, end - base);
    int sreg = csr[min(base + lane, N_ET - 1)];
    int jj = 0;
    for (; jj + 8 <= cnt; jj += 8){
      int s0 = __shfl(sreg, jj);
      int s1 = __shfl(sreg, jj + 1);
      int s2 = __shfl(sreg, jj + 2);
      int s3 = __shfl(sreg, jj + 3);
      int s4 = __shfl(sreg, jj + 4);
      int s5 = __shfl(sreg, jj + 5);
      int s6 = __shfl(sreg, jj + 6);
      int s7 = __shfl(sreg, jj + 7);
      uint h0 = h32[(size_t)s0 * 64 + lane];
      uint h1 = h32[(size_t)s1 * 64 + lane];
      uint h2 = h32[(size_t)s2 * 64 + lane];
      uint h3 = h32[(size_t)s3 * 64 + lane];
      uint h4 = h32[(size_t)s4 * 64 + lane];
      uint h5 = h32[(size_t)s5 * 64 + lane];
      uint h6 = h32[(size_t)s6 * 64 + lane];
      uint h7 = h32[(size_t)s7 * 64 + lane];
      ushort a0 = as16[(size_t)s0 * 8 + myh];
      ushort a1 = as16[(size_t)s1 * 8 + myh];
      ushort a2 = as16[(size_t)s2 * 8 + myh];
      ushort a3 = as16[(size_t)s3 * 8 + myh];
      ushort a4 = as16[(size_t)s4 * 8 + myh];
      ushort a5 = as16[(size_t)s5 * 8 + myh];
      ushort a6 = as16[(size_t)s6 * 8 + myh];
      ushort a7 = as16[(size_t)s7 * 8 + myh];
      __builtin_amdgcn_sched_barrier(0);   // all 16 loads issue before math
#define EDGE(AA, HH)                                              \
      { float e = __half2float(*(__half*)&(AA)) + ad;             \
        e = e > 0.f ? e : NEG * e;                                \
        float p = __expf(fminf(e, 30.f));                         \
        float2 hv = __half22float2(*(__half2*)&(HH));             \
        den += p; acc0 += p * hv.x; acc1 += p * hv.y; }
      EDGE(a0, h0) EDGE(a1, h1) EDGE(a2, h2) EDGE(a3, h3)
      EDGE(a4, h4) EDGE(a5, h5) EDGE(a6, h6) EDGE(a7, h7)
#undef EDGE
    }
    for (; jj < cnt; jj++){
      int s0 = __shfl(sreg, jj);
      uint h0 = h32[(size_t)s0 * 64 + lane];
      ushort a0 = as16[(size_t)s0 * 8 + myh];
      float e = __half2float(*(__half*)&a0) + ad;
      e = e > 0.f ? e : NEG * e;
      float p = __expf(fminf(e, 30.f));
      float2 hv = __half22float2(*(__half2*)&h0);
      den += p; acc0 += p * hv.x; acc1 += p * hv.y;
    }
  }

  float inv = (den > 0.f) ? (1.0f / den) : 0.f;   // den>0 via self-loop
  float v0 = acc0 * inv, v1 = acc1 * inv;
  // head mean: sum over lane bits 3,4,5 (heads)
  v0 += __shfl_xor(v0, 8);  v1 += __shfl_xor(v1, 8);
  v0 += __shfl_xor(v0, 16); v1 += __shfl_xor(v1, 16);
  v0 += __shfl_xor(v0, 32); v1 += __shfl_xor(v1, 32);
  if (lane < 8){
    int c0 = lane * 2;
    float o0 = v0 * 0.125f + scrub(ldf(bias, c0, f32));
    float o1 = v1 * 0.125f + scrub(ldf(bias, c0 + 1, f32));
    o0 = o0 > 0.f ? o0 : (__expf(o0) - 1.0f);
    o1 = o1 > 0.f ? o1 : (__expf(o1) - 1.0f);
    int g = ldid(batch, n, b64);
    if ((uint)g < N_G){
      atomicAdd(&pool[g * 16 + c0],     scrub(o0));
      atomicAdd(&pool[g * 16 + c0 + 1], scrub(o1));
      if (lane == 0) atomicAdd(&cntg[g], 1.0f);
    }
  }
}

// ---- final: divide by counts, write FP32 (reference output dtype) ----
__global__ void k_final(const float* __restrict__ pool, const float* __restrict__ cntg,
                        float* __restrict__ out){
  int i = blockIdx.x * blockDim.x + threadIdx.x;
  if (i >= N_G * OUTC) return;
  int g = i >> 4;
  out[i] = scrub(pool[i] / fmaxf(cntg[g], 1.0f));
}

// -----------------------------------------------------------------------------
extern "C" void kernel_launch(void* const* d_in, const int* in_sizes, int n_in,
                              void* d_out, int out_size, void* d_ws, size_t ws_size,
                              hipStream_t stream){
  (void)in_sizes; (void)n_in; (void)out_size; (void)ws_size;
  const void* x     = d_in[0];
  const int*  ei    = (const int*)d_in[1];
  const int*  batch = (const int*)d_in[2];
  const void* gamma = d_in[3];
  const void* beta  = d_in[4];
  const void* W     = d_in[5];
  const void* att_s = d_in[6];
  const void* att_d = d_in[7];
  const void* bias  = d_in[8];

  // ws total ~36.9 MB (R4-proven safe). h16 tightly packed; csr last.
  char* ws = (char*)d_ws;
  size_t off = 0;
  auto alloc = [&](size_t b){ size_t r = off; off += (b + 255) & ~(size_t)255; return r; };
  int*    flags   = (int*)(ws + alloc(4 * 4));
  float*  stats   = (float*)(ws + alloc(256 * 4));
  float*  Wp      = (float*)(ws + alloc(16384 * 4));
  float*  bp      = (float*)(ws + alloc(128 * 4));
  float*  pool    = (float*)(ws + alloc(N_G * 16 * 4));
  float*  cntg    = (float*)(ws + alloc(N_G * 4));
  int*    chunk   = (int*)(ws + alloc(4096 * 4));
  int*    offsets = (int*)(ws + alloc((size_t)(N_NODES + 1) * 4));
  int*    deg     = (int*)(ws + alloc((size_t)N_NODES * 4));
  int*    cursor  = (int*)(ws + alloc((size_t)N_NODES * 4));
  __half* a_src16 = (__half*)(ws + alloc((size_t)N_NODES * 8 * 2));
  __half* a_dst16 = (__half*)(ws + alloc((size_t)N_NODES * 8 * 2));
  __half* h16     = (__half*)(ws + alloc((size_t)N_NODES * 128 * 2));
  int*    csr     = (int*)(ws + alloc((size_t)N_ET * 4));

  hipMemsetAsync(stats,  0, 256 * 4, stream);
  hipMemsetAsync(deg,    0, (size_t)N_NODES * 4, stream);
  hipMemsetAsync(cursor, 0, (size_t)N_NODES * 4, stream);
  hipMemsetAsync(pool,   0, N_G * 16 * 4, stream);
  hipMemsetAsync(cntg,   0, N_G * 4, stream);

  k_detect<<<1, 256, 0, stream>>>((const uint*)x, ei, batch, flags);
  k_bn_stats<<<512, 256, 0, stream>>>(x, flags, stats);
  k_prep<<<1, 128, 0, stream>>>(stats, gamma, beta, W, flags, Wp, bp);
  k_gemm<<<(N_NODES + 127) / 128, 256, 0, stream>>>(x, Wp, bp, flags, h16);
  k_attn<<<(N_NODES * 8) / 256, 256, 0, stream>>>(h16, att_s, att_d, flags, a_src16, a_dst16);
  k_deg<<<1024, 256, 0, stream>>>(ei, flags, deg);
  k_scan1<<<(NCHUNK + 255) / 256, 256, 0, stream>>>(deg, chunk);
  k_scan2<<<1, 1024, 0, stream>>>(chunk);
  k_scan3<<<(NCHUNK + 255) / 256, 256, 0, stream>>>(deg, chunk, offsets);
  k_scatter<<<1024, 256, 0, stream>>>(ei, flags, offsets, cursor, csr);
  k_msg<<<N_NODES / 4, 256, 0, stream>>>(offsets, csr, a_src16, a_dst16, h16, bias, batch, flags, pool, cntg);
  k_final<<<(N_G * OUTC + 255) / 256, 256, 0, stream>>>(pool, cntg, (float*)d_out);
}